// Round 3
// baseline (154.365 us; speedup 1.0000x reference)
//
#include <hip/hip_runtime.h>
#include <math.h>

// FLIFP: fractional LIF forward, exp-sum memory kernel (K=32), O(K) per step.
// R3: split each neuron's 32 states across 4 lanes (8/lane) -> 512 waves
// (was 128), DPP quad-butterfly for the memory dot, prefetch distance 16.
// R2 was latency/issue-bound with 7/8 of SIMDs empty.

#define K_EXP 32
#define KL 8          // states per lane
#define T_STEPS 1024
#define L_DIM 1024
#define B_DIM 8
#define PF 16         // prefetch distance (steps); 16*~70cy > 900cy HBM latency

struct Coefs {
    float rho[K_EXP];   // rho_k = exp(-s_k)
    float arho[K_EXP];  // A_k * rho_k
};

__device__ __forceinline__ float quad_reduce(float x) {
    // butterfly over the 4 lanes of a quad via DPP quad_perm (off the LDS pipe)
    int t1 = __builtin_amdgcn_mov_dpp(__builtin_bit_cast(int, x), 0xB1, 0xF, 0xF, true); // [1,0,3,2]
    float s = x + __builtin_bit_cast(float, t1);
    int t2 = __builtin_amdgcn_mov_dpp(__builtin_bit_cast(int, s), 0x4E, 0xF, 0xF, true); // [2,3,0,1]
    return s + __builtin_bit_cast(float, t2);
}

__global__ __launch_bounds__(64) void flifp_kernel(
    const float* __restrict__ I,
    float* __restrict__ spk,
    float* __restrict__ vout,
    Coefs c, float coef)
{
    const int gtid = blockIdx.x * 64 + threadIdx.x;
    const int neuron = gtid >> 2;            // 0..8191
    const int sub = threadIdx.x & 3;         // which 8-state group
    const int b = neuron >> 10;
    const int l = neuron & (L_DIM - 1);
    const size_t base = ((size_t)b << 20) + (size_t)l;
    const float* Ip = I + base;
    float* sp = spk + base;
    float* vp = vout + base;

    const float THR = -50.0f;
    const float VINIT = -70.0f;
    const float VL = -70.0f;
    const float GL = 0.025f;

    // per-lane coefficient slice, compile-time indices + cndmask select (no scratch)
    float rho[KL], arho[KL];
#pragma unroll
    for (int j = 0; j < KL; ++j) {
        float ra = (sub & 1) ? c.rho[8 + j]  : c.rho[j];
        float rb = (sub & 1) ? c.rho[24 + j] : c.rho[16 + j];
        rho[j] = (sub & 2) ? rb : ra;
        float aa = (sub & 1) ? c.arho[8 + j]  : c.arho[j];
        float ab = (sub & 1) ? c.arho[24 + j] : c.arho[16 + j];
        arho[j] = (sub & 2) ? ab : aa;
    }

    // t = 0
    if (sub == 0) vp[0] = VINIT;
    if (sub == 1) sp[0] = 0.0f;

    // t = 1: V1 = V0 + 0.005*(-V0 + I0*40)
    float I0 = Ip[0];
    float V = VINIT + 0.005f * (-VINIT + I0 * 40.0f);
    if (sub == 0) vp[(size_t)1 << 10] = V;
    if (sub == 1) sp[(size_t)1 << 10] = (V - THR > 0.0f) ? 1.0f : 0.0f;

    float d = V - VINIT;   // d1 (pre-reset delta)

    float q[KL];
#pragma unroll
    for (int j = 0; j < KL; ++j) q[j] = d;

    auto step = [&](int t, float In) {
        // partial dot over this lane's 8 states (two 4-deep chains)
        float m0 = 0.0f, m1 = 0.0f;
#pragma unroll
        for (int j = 0; j < KL; j += 2) {
            m0 = fmaf(arho[j],     q[j],     m0);
            m1 = fmaf(arho[j + 1], q[j + 1], m1);
        }
        float mem = quad_reduce(m0 + m1);    // full sum on all 4 lanes

        float gate20 = (V - THR > 0.0f) ? 20.0f : 0.0f;
        float Vpre = fmaf(coef, fmaf(-GL, V - VL, In), V) - mem;
        d = Vpre - V;
        V = Vpre - gate20;

        if (sub == 0) vp[(size_t)t << 10] = V;
        if (sub == 1) sp[(size_t)t << 10] = (V - THR > 0.0f) ? 1.0f : 0.0f;

#pragma unroll
        for (int j = 0; j < KL; ++j) q[j] = fmaf(rho[j], q[j], d);
    };

    // initial fill: I[2..2+PF-1]
    float Ibuf[PF];
#pragma unroll
    for (int i = 0; i < PF; ++i) Ibuf[i] = Ip[(size_t)(2 + i) << 10];

    // main: batches of PF steps, reload each slot PF steps ahead (in place, no copies)
    for (int t0 = 2; t0 + PF <= T_STEPS; t0 += PF) {
#pragma unroll
        for (int i = 0; i < PF; ++i) {
            int tn = t0 + PF + i;
            tn = (tn < T_STEPS) ? tn : (T_STEPS - 1);   // keep address valid
            float cur = Ibuf[i];
            Ibuf[i] = Ip[(size_t)tn << 10];
            step(t0 + i, cur);
        }
    }

    // tail: t = 1010..1023 (14 steps), values already in Ibuf[0..13]
#pragma unroll
    for (int i = 0; i < 14; ++i) step(1010 + i, Ibuf[i]);
}

static void make_coefs(Coefs* c, float* coef_out)
{
    const double Cc = 0.8 / tgamma(0.2);     // 0.8 / Gamma(0.2)
    const double delta = 0.25;
    const double x0 = -4.25;                 // 32 exp-sinh nodes: x in [-4.25, 3.5]
    for (int k = 0; k < K_EXP; ++k) {
        double x = x0 + delta * (double)k;
        double s = exp(x - exp(-x));
        double em = exp(-s);
        double diff = em * (-expm1(-s));     // e^{-s} - e^{-2s}, stable for tiny s
        double A = Cc * delta * pow(s, -1.8) * diff * s * (1.0 + exp(-x));
        c->rho[k]  = (float)em;
        c->arho[k] = (float)(A * em);
    }
    *coef_out = (float)(pow(0.1, 0.2) * tgamma(1.8) / 0.5);   // DT^a * Gamma(2-a) / CM
}

extern "C" void kernel_launch(void* const* d_in, const int* in_sizes, int n_in,
                              void* d_out, int out_size, void* d_ws, size_t ws_size,
                              hipStream_t stream)
{
    (void)in_sizes; (void)n_in; (void)d_ws; (void)ws_size;

    const float* I = (const float*)d_in[0];
    float* out0 = (float*)d_out;                                   // spikes [B,T,L]
    float* out1 = out0 + (size_t)B_DIM * T_STEPS * L_DIM;          // voltage [B,T,L]

    Coefs c;
    float coef;
    make_coefs(&c, &coef);

    const int threads = B_DIM * L_DIM * 4;   // 4 lanes per neuron
    flifp_kernel<<<threads / 64, 64, 0, stream>>>(I, out0, out1, c, coef);
}

// Round 6
// 104.330 us; speedup vs baseline: 1.4796x; 1.4796x over previous
//
#include <hip/hip_runtime.h>
#include <math.h>

// FLIFP: fractional LIF forward, exp-sum memory kernel, O(K) per step.
// R6: half-wave split (2 lanes/neuron, 16 states each, K=32 proven quadrature)
// with the cross-half combine done by __shfl_xor(x,32) — guaranteed semantics.
// R4/R5 failed (absmax 3.0-3.5) with permlane32_swap-based combine at BOTH
// K=16 and K=32 -> the permlane usage, not the quadrature, was broken.

#define K_EXP 32
#define KL 16         // states per lane (half-wave split)
#define T_STEPS 1024
#define L_DIM 1024
#define B_DIM 8
#define PF 16         // prefetch distance (steps)

struct Coefs {
    float rho[K_EXP];   // rho_k = exp(-s_k)
    float arho[K_EXP];  // A_k * rho_k
};

__device__ __forceinline__ float half_swap_add(float x) {
    // partner = lane ^ 32; commutative sum -> bitwise-identical result on both
    // halves, keeping the redundant V recurrences in exact lockstep.
    return x + __shfl_xor(x, 32);
}

__global__ __launch_bounds__(64) void flifp_kernel(
    const float* __restrict__ I,
    float* __restrict__ spk,
    float* __restrict__ vout,
    Coefs c, float coef)
{
    const int lane = threadIdx.x;
    const int half = lane >> 5;              // 0: voltage role, 1: spike role
    const int neuron = blockIdx.x * 32 + (lane & 31);   // 0..8191
    const int b = neuron >> 10;
    const int l = neuron & (L_DIM - 1);
    const size_t base = ((size_t)b << 20) + (size_t)l;  // b*T*L + l
    const float* Ip = I + base;
    // role-split output pointer: half0 writes voltage, half1 writes spikes
    float* outp = (half ? spk : vout) + base;

    const float THR = -50.0f;
    const float VINIT = -70.0f;
    const float VL = -70.0f;
    const float GL = 0.025f;

    // per-lane coefficient slice (compile-time indices, one cndmask each)
    float rho[KL], arho[KL];
#pragma unroll
    for (int j = 0; j < KL; ++j) {
        rho[j]  = half ? c.rho[KL + j]  : c.rho[j];
        arho[j] = half ? c.arho[KL + j] : c.arho[j];
    }

    // t = 0: V0 = -70, spike 0
    outp[0] = half ? 0.0f : VINIT;

    // t = 1: V1 = V0 + 0.005*(-V0 + I0*40)
    float I0 = Ip[0];
    float V = VINIT + 0.005f * (-VINIT + I0 * 40.0f);
    {
        float spike1 = (V - THR > 0.0f) ? 1.0f : 0.0f;
        outp[(size_t)1 << 10] = half ? spike1 : V;
    }

    float d = V - VINIT;   // d1 (pre-reset delta)

    float q[KL];
#pragma unroll
    for (int j = 0; j < KL; ++j) q[j] = d;

    auto step = [&](int t, float In) {
        // partial dot over this lane's 16 states (4 independent 4-deep chains)
        float m0 = 0.0f, m1 = 0.0f, m2 = 0.0f, m3 = 0.0f;
#pragma unroll
        for (int j = 0; j < KL; j += 4) {
            m0 = fmaf(arho[j],     q[j],     m0);
            m1 = fmaf(arho[j + 1], q[j + 1], m1);
            m2 = fmaf(arho[j + 2], q[j + 2], m2);
            m3 = fmaf(arho[j + 3], q[j + 3], m3);
        }
        float mem = half_swap_add((m0 + m1) + (m2 + m3));  // full K=32 dot

        float gate20 = (V - THR > 0.0f) ? 20.0f : 0.0f;    // gate on V_old
        float Vpre = fmaf(coef, fmaf(-GL, V - VL, In), V) - mem;
        d = Vpre - V;
        V = Vpre - gate20;

        float spike = (V - THR > 0.0f) ? 1.0f : 0.0f;
        outp[(size_t)t << 10] = half ? spike : V;

#pragma unroll
        for (int j = 0; j < KL; ++j) q[j] = fmaf(rho[j], q[j], d);
    };

    // initial fill: I[2..2+PF-1]
    float Ibuf[PF];
#pragma unroll
    for (int i = 0; i < PF; ++i) Ibuf[i] = Ip[(size_t)(2 + i) << 10];

    // main: batches of PF steps, reload each slot PF steps ahead (in place)
    for (int t0 = 2; t0 + PF <= T_STEPS; t0 += PF) {
#pragma unroll
        for (int i = 0; i < PF; ++i) {
            int tn = t0 + PF + i;
            tn = (tn < T_STEPS) ? tn : (T_STEPS - 1);   // keep address valid
            float cur = Ibuf[i];
            Ibuf[i] = Ip[(size_t)tn << 10];
            step(t0 + i, cur);
        }
    }

    // tail: t = 1010..1023 (14 steps), values already in Ibuf[0..13]
#pragma unroll
    for (int i = 0; i < 14; ++i) step(1010 + i, Ibuf[i]);
}

static void make_coefs(Coefs* c, float* coef_out)
{
    const double Cc = 0.8 / tgamma(0.2);     // 0.8 / Gamma(0.2)
    const double delta = 0.25;
    const double x0 = -4.25;                 // 32 exp-sinh nodes: x in [-4.25, 3.5]
    for (int k = 0; k < K_EXP; ++k) {
        double x = x0 + delta * (double)k;
        double s = exp(x - exp(-x));
        double em = exp(-s);
        double diff = em * (-expm1(-s));     // e^{-s} - e^{-2s}, stable for tiny s
        double A = Cc * delta * pow(s, -1.8) * diff * s * (1.0 + exp(-x));
        c->rho[k]  = (float)em;
        c->arho[k] = (float)(A * em);
    }
    *coef_out = (float)(pow(0.1, 0.2) * tgamma(1.8) / 0.5);   // DT^a * Gamma(2-a) / CM
}

extern "C" void kernel_launch(void* const* d_in, const int* in_sizes, int n_in,
                              void* d_out, int out_size, void* d_ws, size_t ws_size,
                              hipStream_t stream)
{
    (void)in_sizes; (void)n_in; (void)d_ws; (void)ws_size;

    const float* I = (const float*)d_in[0];
    float* out0 = (float*)d_out;                                   // spikes [B,T,L]
    float* out1 = out0 + (size_t)B_DIM * T_STEPS * L_DIM;          // voltage [B,T,L]

    Coefs c;
    float coef;
    make_coefs(&c, &coef);

    const int threads = B_DIM * L_DIM * 2;   // 2 lanes per neuron (half-wave split)
    flifp_kernel<<<threads / 64, 64, 0, stream>>>(I, out0, out1, c, coef);
}